// Round 7
// baseline (414.482 us; speedup 1.0000x reference)
//
#include <hip/hip_runtime.h>
#include <hip/hip_bf16.h>

#define B_  32
#define LK  2048
#define DM  1024
#define NH  16

typedef __attribute__((ext_vector_type(8))) short short8;
typedef __attribute__((ext_vector_type(4))) float f32x4;

__device__ __forceinline__ ushort f2bf(float f){
  union { float f; unsigned u; } v; v.f = f;
  unsigned u = v.u;
  u += 0x7fffu + ((u >> 16) & 1u);   // RNE
  return (ushort)(u >> 16);
}

__device__ __forceinline__ short8 pack8(f32x4 a, f32x4 b){
  union { __hip_bfloat162 h[4]; short8 s; } r;
  r.h[0] = __float22bfloat162_rn(make_float2(a[0], a[1]));
  r.h[1] = __float22bfloat162_rn(make_float2(a[2], a[3]));
  r.h[2] = __float22bfloat162_rn(make_float2(b[0], b[1]));
  r.h[3] = __float22bfloat162_rn(make_float2(b[2], b[3]));
  return r.s;
}

__device__ __forceinline__ void gll16(const void* g, void* l){
  __builtin_amdgcn_global_load_lds(
      (__attribute__((address_space(1))) void*)g,
      (__attribute__((address_space(3))) void*)l, 16, 0, 0);
}

#define C2LOG2E 2.8853900817779268f  /* 2*log2(e) */

// ---- K0: merged prepass. blocks 0..1023: Wk->wkt transpose+bf16. 1024..1151: qup GEMV.
__global__ __launch_bounds__(256) void k_pre(const float* __restrict__ Wk, ushort* __restrict__ wkt,
                                             const float* __restrict__ query, const float* __restrict__ Wq,
                                             const float* __restrict__ bq, float* __restrict__ qup){
  __shared__ float smem[1056];
  int bid = blockIdx.x;
  int t = threadIdx.x;
  if (bid < 1024){
    float (*tile)[33] = (float(*)[33])smem;
    int n0 = (bid & 31) * 32, k0 = (bid >> 5) * 32;
    int tx = t & 31, ty = t >> 5;
#pragma unroll
    for (int r = 0; r < 4; ++r)
      tile[ty + 8*r][tx] = Wk[(size_t)(k0 + ty + 8*r) * DM + n0 + tx];
    __syncthreads();
#pragma unroll
    for (int r = 0; r < 4; ++r){
      int n = ty + 8*r;
      wkt[(size_t)(n0 + n) * DM + k0 + tx] = f2bf(tile[tx][n]);
    }
  } else {
    int bb = bid - 1024;
    int b = bb >> 2, nc = bb & 3;
    float* q = smem;
#pragma unroll
    for (int j = 0; j < 4; ++j) q[j*256 + t] = query[(size_t)b*DM + j*256 + t];
    __syncthreads();
    int n = nc*256 + t;
    float acc = bq[n];
#pragma unroll 8
    for (int k = 0; k < DM; ++k) acc += q[k] * Wq[(size_t)k*DM + n];
    qup[(size_t)b*DM + n] = acc;
  }
}

// ---- K2: MFMA GEMM, key f32 read directly.
// A: reg-staged f32->bf16, single 16KB buffer; B: gll DOUBLE-buffered (2x16KB) so its
// load latency hides under the MFMA phase (the phase-end barrier's vmcnt(0) lands after
// ~650cy of ds_read+MFMA). Phase 1 is just the A ds_write + barrier (~100cy).
// Verified conflict-free involution swizzle; T1 XCD grouping. 48KB LDS -> 3 blocks/CU.
__global__ __launch_bounds__(256, 3) void k_gemm(
    const float* __restrict__ key, const ushort* __restrict__ wkt,
    const float* __restrict__ qup, const float* __restrict__ bk,
    const float* __restrict__ wsc, float* __restrict__ scores)
{
  __shared__ ushort ldsA[8192];      // 16 KB, 128 rows x 64 k, swizzled image
  __shared__ ushort ldsB[2][8192];   // 2 x 16 KB double buffer
  const int tid  = threadIdx.x;
  const int lane = tid & 63;
  const int wid  = tid >> 6;
  const int wr   = wid >> 1, wc = wid & 1;
  const int l15  = lane & 15, l16 = lane >> 4;

  // T1: XCD-grouped decode (hw round-robin: xcd ~ bid&7); 8 ct-siblings share key panel + XCD L2
  const int bid = blockIdx.x;
  const int xcd = bid & 7;
  const int j   = bid >> 3;             // 0..511
  const int ct  = j & 7;                // column tile / head pair
  const int rb  = xcd * 64 + (j >> 3);  // row panel 0..511
  const size_t row0 = (size_t)rb * 128;
  const int b  = rb >> 4;
  const int l0 = (rb & 15) * 128;

  // staging lane geometry (A and B share it): row-in-group g8, pre-swizzled k8 slot
  const int g8  = lane >> 3;            // 0..7
  const int sk8 = (lane & 7) ^ g8;      // involution: source slot == written-image slot
  const ushort* bbase = wkt + (size_t)(ct*128 + wid*32 + g8) * DM + sk8*8;
  const float*  akey  = key + (row0 + (size_t)(wid*32 + g8)) * DM + sk8*8;

  float qbc[4], wm2[4], wsum = 0.f;
#pragma unroll
  for (int ni = 0; ni < 4; ++ni){
    int n = ct*128 + wc*64 + ni*16 + l15;
    float w = wsc[ni*16 + l15];
    qbc[ni] = (qup[(size_t)b*DM + n] + bk[n]) * C2LOG2E;
    wm2[ni] = -2.f * w;
    wsum   += w;
  }

  f32x4 acc[4][4];
#pragma unroll
  for (int mi = 0; mi < 4; ++mi)
#pragma unroll
    for (int ni = 0; ni < 4; ++ni) acc[mi][ni] = (f32x4){0.f,0.f,0.f,0.f};

  // prologue: B(0) gll into buf0; A(0) -> regs -> pack
  short8 sa[4];
#pragma unroll
  for (int c = 0; c < 4; ++c)
    gll16(bbase + (size_t)c*8*DM, (char*)ldsB[0] + wid*4096 + c*1024);
#pragma unroll
  for (int j4 = 0; j4 < 4; ++j4){
    const float* ap = akey + (size_t)j4*8*DM;
    f32x4 a0 = *(const f32x4*)ap, a1 = *(const f32x4*)(ap + 4);
    sa[j4] = pack8(a0, a1);
  }

  const int sw = (l15 & 7) << 4;   // read-side XOR (row&7)<<4

  for (int kt = 0; kt < 16; ++kt){
    // phase 1: write A(kt) from packed regs; barrier drains it (+ any outstanding gll)
#pragma unroll
    for (int j4 = 0; j4 < 4; ++j4)
      *(short8*)((char*)ldsA + (wid*4 + j4)*1024 + lane*16) = sa[j4];
    __syncthreads();

    // phase 2: issue B(kt+1) gll + A(kt+1) f32 loads (both hide under ds_read+MFMA)
    f32x4 a0[4], a1[4];
    if (kt < 15){
#pragma unroll
      for (int c = 0; c < 4; ++c)
        gll16(bbase + (size_t)(kt+1)*64 + (size_t)c*8*DM,
              (char*)ldsB[(kt+1) & 1] + wid*4096 + c*1024);
#pragma unroll
      for (int j4 = 0; j4 < 4; ++j4){
        const float* ap = akey + (size_t)j4*8*DM + (kt+1)*64;
        a0[j4] = *(const f32x4*)ap; a1[j4] = *(const f32x4*)(ap + 4);
      }
    }

    const char* Bc = (const char*)ldsB[kt & 1];
    short8 af[4][2], bfr[4][2];
#pragma unroll
    for (int mi = 0; mi < 4; ++mi){
      int row = wr*64 + mi*16 + l15;
      af[mi][0] = *(const short8*)((const char*)ldsA + row*128 + ((l16*16) ^ sw));
      af[mi][1] = *(const short8*)((const char*)ldsA + row*128 + ((64 + l16*16) ^ sw));
    }
#pragma unroll
    for (int ni = 0; ni < 4; ++ni){
      int col = wc*64 + ni*16 + l15;
      bfr[ni][0] = *(const short8*)(Bc + col*128 + ((l16*16) ^ sw));
      bfr[ni][1] = *(const short8*)(Bc + col*128 + ((64 + l16*16) ^ sw));
    }
#pragma unroll
    for (int kk = 0; kk < 2; ++kk)
#pragma unroll
      for (int mi = 0; mi < 4; ++mi)
#pragma unroll
        for (int ni = 0; ni < 4; ++ni)
          acc[mi][ni] = __builtin_amdgcn_mfma_f32_16x16x32_bf16(af[mi][kk], bfr[ni][kk], acc[mi][ni], 0, 0, 0);

    if (kt < 15){
#pragma unroll
      for (int j4 = 0; j4 < 4; ++j4)
        sa[j4] = pack8(a0[j4], a1[j4]);   // f32 regs die here; only sa crosses barrier
    }
    __syncthreads();   // readers done with ldsA/ldsB[cur]; B(kt+1) gll drains (hidden)
  }

  // epilogue: scores = sum_col w*tanh(acc + q + bk), native exp2/rcp form
#pragma unroll
  for (int mi = 0; mi < 4; ++mi){
    f32x4 s = {wsum, wsum, wsum, wsum};
#pragma unroll
    for (int ni = 0; ni < 4; ++ni)
#pragma unroll
      for (int r = 0; r < 4; ++r){
        float a  = fmaf(acc[mi][ni][r], C2LOG2E, qbc[ni]);
        float e  = __builtin_amdgcn_exp2f(a);
        float rc = __builtin_amdgcn_rcpf(e + 1.f);
        s[r] = fmaf(wm2[ni], rc, s[r]);
      }
#pragma unroll
    for (int r = 0; r < 4; ++r){
      float v = s[r];
      v += __shfl_xor(v, 1);
      v += __shfl_xor(v, 2);
      v += __shfl_xor(v, 4);
      v += __shfl_xor(v, 8);
      s[r] = v;
    }
    if (l15 == 0)
      *(f32x4*)(scores + (size_t)(b*NH + ct*2 + wc)*LK + l0 + wr*64 + mi*16 + l16*4) = s;
  }
}

// ---- K3: masked softmax over l -> attn (output #2)
__global__ __launch_bounds__(256) void k_softmax(const float* __restrict__ scores, const int* __restrict__ mask,
                                                 float* __restrict__ attn){
  int bh = blockIdx.x; int b = bh >> 4;
  const float* s = scores + (size_t)bh * LK;
  const int*   m = mask + (size_t)b * LK;
  float*       a = attn + (size_t)bh * LK;
  int t = threadIdx.x;
  __shared__ float red[8];

  float sv[8]; int mv[8];
  float lmax = -1e30f;
#pragma unroll
  for (int j = 0; j < 8; ++j){
    int i = j*256 + t;
    sv[j] = s[i]; mv[j] = m[i];
    if (!mv[j]) lmax = fmaxf(lmax, sv[j]);
  }
#pragma unroll
  for (int off = 32; off >= 1; off >>= 1) lmax = fmaxf(lmax, __shfl_xor(lmax, off));
  if ((t & 63) == 0) red[t >> 6] = lmax;
  __syncthreads();
  lmax = fmaxf(fmaxf(red[0], red[1]), fmaxf(red[2], red[3]));

  float ev[8]; float lsum = 0.f;
#pragma unroll
  for (int j = 0; j < 8; ++j){
    ev[j] = mv[j] ? 0.f : __expf(sv[j] - lmax);
    lsum += ev[j];
  }
#pragma unroll
  for (int off = 32; off >= 1; off >>= 1) lsum += __shfl_xor(lsum, off);
  if ((t & 63) == 0) red[4 + (t >> 6)] = lsum;
  __syncthreads();
  lsum = red[4] + red[5] + red[6] + red[7];
  float inv = 1.f / lsum;
#pragma unroll
  for (int j = 0; j < 8; ++j) a[j*256 + t] = ev[j] * inv;
}

// ---- K4: context partials: part[b,ch,c] = sum_{l in chunk} attn[b,h(c),l] * value[b,l,c]
__global__ __launch_bounds__(256) void k_ctx(const float* __restrict__ value, const float* __restrict__ attn,
                                             float* __restrict__ part){
  int b = blockIdx.x >> 4, ch = blockIdx.x & 15;
  int t = threadIdx.x;
  int c4 = t * 4;
  int head = t >> 4;
  const float* ap = attn + (size_t)(b*NH + head)*LK + ch*128;
  const float* vp = value + ((size_t)b*LK + ch*128)*DM + c4;
  f32x4 acc = {0.f, 0.f, 0.f, 0.f};
#pragma unroll 4
  for (int l = 0; l < 128; ++l){
    float av = ap[l];
    f32x4 v = *(const f32x4*)(vp + (size_t)l*DM);
#pragma unroll
    for (int j = 0; j < 4; ++j) acc[j] += av * v[j];
  }
  *(f32x4*)(part + (size_t)(b*16 + ch)*DM + c4) = acc;
}

// ---- K6: reduce partials -> context; output = context @ Wf + bf (output #1)
__global__ __launch_bounds__(256) void k_out(const float* __restrict__ part, const float* __restrict__ Wf,
                                             const float* __restrict__ bfv, float* __restrict__ out){
  __shared__ float ctx[DM];
  int b = blockIdx.x >> 2, nc = blockIdx.x & 3;
  int t = threadIdx.x;
#pragma unroll
  for (int j = 0; j < 4; ++j){
    int k = j*256 + t;
    float s = 0.f;
#pragma unroll
    for (int c = 0; c < 16; ++c) s += part[(size_t)(b*16 + c)*DM + k];
    ctx[k] = s;
  }
  __syncthreads();
  int n = nc*256 + t;
  float acc = bfv[n];
#pragma unroll 8
  for (int k = 0; k < DM; ++k) acc += ctx[k] * Wf[(size_t)k*DM + n];
  out[(size_t)b*DM + n] = acc;
}

extern "C" void kernel_launch(void* const* d_in, const int* in_sizes, int n_in,
                              void* d_out, int out_size, void* d_ws, size_t ws_size,
                              hipStream_t stream){
  (void)in_sizes; (void)n_in; (void)out_size; (void)ws_size;
  const float* key   = (const float*)d_in[0];
  const float* value = (const float*)d_in[1];
  const float* query = (const float*)d_in[2];
  const int*   mask  = (const int*)d_in[3];
  const float* Wk    = (const float*)d_in[4];
  const float* bk    = (const float*)d_in[5];
  const float* Wq    = (const float*)d_in[6];
  const float* bq    = (const float*)d_in[7];
  const float* wsc   = (const float*)d_in[8];
  // d_in[9] = b_score: softmax-invariant, unused
  const float* Wf    = (const float*)d_in[10];
  const float* bfv   = (const float*)d_in[11];

  float* out0 = (float*)d_out;
  float* attn = out0 + (size_t)B_ * DM;   // [B,H,1,Lk] region

  char* ws = (char*)d_ws;
  ushort* wkt  = (ushort*)(ws);                                    // 2 MB
  float*  qup  = (float*)(ws + (2u<<20));                          // 128 KB
  float*  scr  = (float*)(ws + (2u<<20) + (128u<<10));             // 4 MB
  float*  part = (float*)(ws + (2u<<20) + (128u<<10) + (4u<<20));  // 2 MB

  k_pre<<<1152, 256, 0, stream>>>(Wk, wkt, query, Wq, bq, qup);
  k_gemm<<<4096, 256, 0, stream>>>(key, wkt, qup, bk, wsc, scr);
  k_softmax<<<512, 256, 0, stream>>>(scr, mask, attn);
  k_ctx<<<512, 256, 0, stream>>>(value, attn, part);
  k_out<<<128, 256, 0, stream>>>(part, Wf, bfv, out0);
}

// Round 8
// 401.125 us; speedup vs baseline: 1.0333x; 1.0333x over previous
//
#include <hip/hip_runtime.h>
#include <hip/hip_bf16.h>

#define B_  32
#define LK  2048
#define DM  1024
#define NH  16

typedef __attribute__((ext_vector_type(8))) short short8;
typedef __attribute__((ext_vector_type(4))) float f32x4;

__device__ __forceinline__ ushort f2bf(float f){
  union { float f; unsigned u; } v; v.f = f;
  unsigned u = v.u;
  u += 0x7fffu + ((u >> 16) & 1u);   // RNE
  return (ushort)(u >> 16);
}

__device__ __forceinline__ short8 pack8(f32x4 a, f32x4 b){
  union { __hip_bfloat162 h[4]; short8 s; } r;
  r.h[0] = __float22bfloat162_rn(make_float2(a[0], a[1]));
  r.h[1] = __float22bfloat162_rn(make_float2(a[2], a[3]));
  r.h[2] = __float22bfloat162_rn(make_float2(b[0], b[1]));
  r.h[3] = __float22bfloat162_rn(make_float2(b[2], b[3]));
  return r.s;
}

__device__ __forceinline__ void gll16(const void* g, void* l){
  __builtin_amdgcn_global_load_lds(
      (__attribute__((address_space(1))) void*)g,
      (__attribute__((address_space(3))) void*)l, 16, 0, 0);
}

#define C2LOG2E 2.8853900817779268f  /* 2*log2(e) */

// ---- K0: merged prepass.
//  blocks [0,1024):    Wk [k][n] f32 -> wkt [n][k] bf16 (transpose+convert)
//  blocks [1024,1152): qup[b][n] = bq[n] + query[b,:] @ Wq[:,n]
//  blocks [1152,5248): key f32 -> keybf bf16, grid-stride x8 (384MB traffic, ~70us)
__global__ __launch_bounds__(256) void k_pre(const float* __restrict__ Wk, ushort* __restrict__ wkt,
                                             const float* __restrict__ query, const float* __restrict__ Wq,
                                             const float* __restrict__ bq, float* __restrict__ qup,
                                             const float* __restrict__ key, ushort* __restrict__ keybf){
  __shared__ float smem[1056];
  int bid = blockIdx.x;
  int t = threadIdx.x;
  if (bid >= 1152){
    int base = bid - 1152;   // 0..4095
#pragma unroll
    for (int it = 0; it < 8; ++it){
      size_t i = (((size_t)(base + it*4096)) * 256 + t) * 8;
      f32x4 a = *(const f32x4*)(key + i);
      f32x4 b = *(const f32x4*)(key + i + 4);
      *(short8*)(keybf + i) = pack8(a, b);
    }
  } else if (bid < 1024){
    float (*tile)[33] = (float(*)[33])smem;
    int n0 = (bid & 31) * 32, k0 = (bid >> 5) * 32;
    int tx = t & 31, ty = t >> 5;
#pragma unroll
    for (int r = 0; r < 4; ++r)
      tile[ty + 8*r][tx] = Wk[(size_t)(k0 + ty + 8*r) * DM + n0 + tx];
    __syncthreads();
#pragma unroll
    for (int r = 0; r < 4; ++r){
      int n = ty + 8*r;
      wkt[(size_t)(n0 + n) * DM + k0 + tx] = f2bf(tile[tx][n]);
    }
  } else {
    int bb = bid - 1024;
    int b = bb >> 2, nc = bb & 3;
    float* q = smem;
#pragma unroll
    for (int j = 0; j < 4; ++j) q[j*256 + t] = query[(size_t)b*DM + j*256 + t];
    __syncthreads();
    int n = nc*256 + t;
    float acc = bq[n];
#pragma unroll 8
    for (int k = 0; k < DM; ++k) acc += q[k] * Wq[(size_t)k*DM + n];
    qup[(size_t)b*DM + n] = acc;
  }
}

// ---- K2: R3-structure MFMA GEMM (the proven-fastest variant) + verified add-ons.
// A (keybf) and B (wkt) both via global_load_lds w16, single 16KB buffer each,
// 2 barriers/K-step, 32KB LDS -> 5 blocks/CU. Pre-swizzled gll sources + XOR read
// (involution verified conflict-free in R4/R6/R7). T1 XCD grouping (ct-siblings
// share key panel on one XCD; FETCH 551->~180MB verified R6/R7).
__global__ __launch_bounds__(256, 5) void k_gemm(
    const ushort* __restrict__ keybf, const ushort* __restrict__ wkt,
    const float* __restrict__ qup, const float* __restrict__ bk,
    const float* __restrict__ wsc, float* __restrict__ scores)
{
  __shared__ ushort ldsA[8192];   // 16 KB, 128 rows x 64 k, swizzled image
  __shared__ ushort ldsB[8192];   // 16 KB
  const int tid  = threadIdx.x;
  const int lane = tid & 63;
  const int wid  = tid >> 6;
  const int wr   = wid >> 1, wc = wid & 1;
  const int l15  = lane & 15, l16 = lane >> 4;

  // T1: hw round-robins xcd = bid&7; keep 8 ct-siblings of one row-panel on one XCD
  const int bid = blockIdx.x;
  const int xcd = bid & 7;
  const int j   = bid >> 3;             // 0..511
  const int ct  = j & 7;                // column tile / head pair (fast index)
  const int rb  = xcd * 64 + (j >> 3);  // row panel 0..511
  const size_t row0 = (size_t)rb * 128;
  const int b  = rb >> 4;
  const int l0 = (rb & 15) * 128;

  // staging lane geometry: row-in-group g8, pre-swizzled k8 source slot (involution)
  const int g8  = lane >> 3;            // 0..7
  const int sk8 = (lane & 7) ^ g8;
  const ushort* abase = keybf + (row0 + (size_t)(wid*32 + g8)) * DM + sk8*8;
  const ushort* bbase = wkt + (size_t)(ct*128 + wid*32 + g8) * DM + sk8*8;
  char* lab = (char*)ldsA + wid*4096;
  char* lbb = (char*)ldsB + wid*4096;

  float qbc[4], wm2[4], wsum = 0.f;
#pragma unroll
  for (int ni = 0; ni < 4; ++ni){
    int n = ct*128 + wc*64 + ni*16 + l15;
    float w = wsc[ni*16 + l15];
    qbc[ni] = (qup[(size_t)b*DM + n] + bk[n]) * C2LOG2E;
    wm2[ni] = -2.f * w;
    wsum   += w;
  }

  f32x4 acc[4][4];
#pragma unroll
  for (int mi = 0; mi < 4; ++mi)
#pragma unroll
    for (int ni = 0; ni < 4; ++ni) acc[mi][ni] = (f32x4){0.f,0.f,0.f,0.f};

  const int sw = (l15 & 7) << 4;   // read-side XOR (row&7)<<4

  for (int kt = 0; kt < 16; ++kt){
    // phase 1: stage A(kt) + B(kt)
#pragma unroll
    for (int c = 0; c < 4; ++c){
      gll16(abase + (size_t)kt*64 + (size_t)c*8*DM, lab + c*1024);
      gll16(bbase + (size_t)kt*64 + (size_t)c*8*DM, lbb + c*1024);
    }
    __syncthreads();   // drains gll; tiles ready

    // phase 2: ds_read (swizzled) + 32 MFMA
    short8 af[4][2], bfr[4][2];
#pragma unroll
    for (int mi = 0; mi < 4; ++mi){
      int row = wr*64 + mi*16 + l15;
      af[mi][0] = *(const short8*)((const char*)ldsA + row*128 + ((l16*16) ^ sw));
      af[mi][1] = *(const short8*)((const char*)ldsA + row*128 + ((64 + l16*16) ^ sw));
    }
#pragma unroll
    for (int ni = 0; ni < 4; ++ni){
      int col = wc*64 + ni*16 + l15;
      bfr[ni][0] = *(const short8*)((const char*)ldsB + col*128 + ((l16*16) ^ sw));
      bfr[ni][1] = *(const short8*)((const char*)ldsB + col*128 + ((64 + l16*16) ^ sw));
    }
#pragma unroll
    for (int kk = 0; kk < 2; ++kk)
#pragma unroll
      for (int mi = 0; mi < 4; ++mi)
#pragma unroll
        for (int ni = 0; ni < 4; ++ni)
          acc[mi][ni] = __builtin_amdgcn_mfma_f32_16x16x32_bf16(af[mi][kk], bfr[ni][kk], acc[mi][ni], 0, 0, 0);

    __syncthreads();   // before overwriting the single buffers
  }

  // epilogue: scores = sum_col w*tanh(acc + q + bk), native exp2/rcp form
#pragma unroll
  for (int mi = 0; mi < 4; ++mi){
    f32x4 s = {wsum, wsum, wsum, wsum};
#pragma unroll
    for (int ni = 0; ni < 4; ++ni)
#pragma unroll
      for (int r = 0; r < 4; ++r){
        float a  = fmaf(acc[mi][ni][r], C2LOG2E, qbc[ni]);
        float e  = __builtin_amdgcn_exp2f(a);
        float rc = __builtin_amdgcn_rcpf(e + 1.f);
        s[r] = fmaf(wm2[ni], rc, s[r]);
      }
#pragma unroll
    for (int r = 0; r < 4; ++r){
      float v = s[r];
      v += __shfl_xor(v, 1);
      v += __shfl_xor(v, 2);
      v += __shfl_xor(v, 4);
      v += __shfl_xor(v, 8);
      s[r] = v;
    }
    if (l15 == 0)
      *(f32x4*)(scores + (size_t)(b*NH + ct*2 + wc)*LK + l0 + wr*64 + mi*16 + l16*4) = s;
  }
}

// ---- K3: masked softmax over l -> attn (output #2)
__global__ __launch_bounds__(256) void k_softmax(const float* __restrict__ scores, const int* __restrict__ mask,
                                                 float* __restrict__ attn){
  int bh = blockIdx.x; int b = bh >> 4;
  const float* s = scores + (size_t)bh * LK;
  const int*   m = mask + (size_t)b * LK;
  float*       a = attn + (size_t)bh * LK;
  int t = threadIdx.x;
  __shared__ float red[8];

  float sv[8]; int mv[8];
  float lmax = -1e30f;
#pragma unroll
  for (int j = 0; j < 8; ++j){
    int i = j*256 + t;
    sv[j] = s[i]; mv[j] = m[i];
    if (!mv[j]) lmax = fmaxf(lmax, sv[j]);
  }
#pragma unroll
  for (int off = 32; off >= 1; off >>= 1) lmax = fmaxf(lmax, __shfl_xor(lmax, off));
  if ((t & 63) == 0) red[t >> 6] = lmax;
  __syncthreads();
  lmax = fmaxf(fmaxf(red[0], red[1]), fmaxf(red[2], red[3]));

  float ev[8]; float lsum = 0.f;
#pragma unroll
  for (int j = 0; j < 8; ++j){
    ev[j] = mv[j] ? 0.f : __expf(sv[j] - lmax);
    lsum += ev[j];
  }
#pragma unroll
  for (int off = 32; off >= 1; off >>= 1) lsum += __shfl_xor(lsum, off);
  if ((t & 63) == 0) red[4 + (t >> 6)] = lsum;
  __syncthreads();
  lsum = red[4] + red[5] + red[6] + red[7];
  float inv = 1.f / lsum;
#pragma unroll
  for (int j = 0; j < 8; ++j) a[j*256 + t] = ev[j] * inv;
}

// ---- K4: context partials: part[b,ch,c] = sum_{l in chunk} attn[b,h(c),l] * value[b,l,c]
__global__ __launch_bounds__(256) void k_ctx(const float* __restrict__ value, const float* __restrict__ attn,
                                             float* __restrict__ part){
  int b = blockIdx.x >> 4, ch = blockIdx.x & 15;
  int t = threadIdx.x;
  int c4 = t * 4;
  int head = t >> 4;
  const float* ap = attn + (size_t)(b*NH + head)*LK + ch*128;
  const float* vp = value + ((size_t)b*LK + ch*128)*DM + c4;
  f32x4 acc = {0.f, 0.f, 0.f, 0.f};
#pragma unroll 4
  for (int l = 0; l < 128; ++l){
    float av = ap[l];
    f32x4 v = *(const f32x4*)(vp + (size_t)l*DM);
#pragma unroll
    for (int j = 0; j < 4; ++j) acc[j] += av * v[j];
  }
  *(f32x4*)(part + (size_t)(b*16 + ch)*DM + c4) = acc;
}

// ---- K6: reduce partials -> context; output = context @ Wf + bf (output #1)
__global__ __launch_bounds__(256) void k_out(const float* __restrict__ part, const float* __restrict__ Wf,
                                             const float* __restrict__ bfv, float* __restrict__ out){
  __shared__ float ctx[DM];
  int b = blockIdx.x >> 2, nc = blockIdx.x & 3;
  int t = threadIdx.x;
#pragma unroll
  for (int j = 0; j < 4; ++j){
    int k = j*256 + t;
    float s = 0.f;
#pragma unroll
    for (int c = 0; c < 16; ++c) s += part[(size_t)(b*16 + c)*DM + k];
    ctx[k] = s;
  }
  __syncthreads();
  int n = nc*256 + t;
  float acc = bfv[n];
#pragma unroll 8
  for (int k = 0; k < DM; ++k) acc += ctx[k] * Wf[(size_t)k*DM + n];
  out[(size_t)b*DM + n] = acc;
}

extern "C" void kernel_launch(void* const* d_in, const int* in_sizes, int n_in,
                              void* d_out, int out_size, void* d_ws, size_t ws_size,
                              hipStream_t stream){
  (void)in_sizes; (void)n_in; (void)out_size; (void)ws_size;
  const float* key   = (const float*)d_in[0];
  const float* value = (const float*)d_in[1];
  const float* query = (const float*)d_in[2];
  const int*   mask  = (const int*)d_in[3];
  const float* Wk    = (const float*)d_in[4];
  const float* bk    = (const float*)d_in[5];
  const float* Wq    = (const float*)d_in[6];
  const float* bq    = (const float*)d_in[7];
  const float* wsc   = (const float*)d_in[8];
  // d_in[9] = b_score: softmax-invariant, unused
  const float* Wf    = (const float*)d_in[10];
  const float* bfv   = (const float*)d_in[11];

  float* out0 = (float*)d_out;
  float* attn = out0 + (size_t)B_ * DM;   // [B,H,1,Lk] region

  char* ws = (char*)d_ws;
  ushort* wkt  = (ushort*)(ws);                                    // 2 MB
  float*  qup  = (float*)(ws + (2u<<20));                          // 128 KB
  float*  scr  = (float*)(ws + (2u<<20) + (128u<<10));             // 4 MB
  float*  part = (float*)(ws + (2u<<20) + (128u<<10) + (4u<<20));  // 2 MB
  const size_t base = (2u<<20) + (128u<<10) + (4u<<20) + (2u<<20); // 8.125 MB
  ushort* keybf = (ushort*)(ws + base);                            // 128 MB (ws >= 136MB proven R2/R3)

  k_pre<<<5248, 256, 0, stream>>>(Wk, wkt, query, Wq, bq, qup, key, keybf);
  k_gemm<<<4096, 256, 0, stream>>>(keybf, wkt, qup, bk, wsc, scr);
  k_softmax<<<512, 256, 0, stream>>>(scr, mask, attn);
  k_ctx<<<512, 256, 0, stream>>>(value, attn, part);
  k_out<<<128, 256, 0, stream>>>(part, Wf, bfv, out0);
}

// Round 9
// 390.723 us; speedup vs baseline: 1.0608x; 1.0266x over previous
//
#include <hip/hip_runtime.h>
#include <hip/hip_bf16.h>

#define B_  32
#define LK  2048
#define DM  1024
#define NH  16

typedef __attribute__((ext_vector_type(8))) short short8;
typedef __attribute__((ext_vector_type(4))) float f32x4;

__device__ __forceinline__ ushort f2bf(float f){
  union { float f; unsigned u; } v; v.f = f;
  unsigned u = v.u;
  u += 0x7fffu + ((u >> 16) & 1u);   // RNE
  return (ushort)(u >> 16);
}

__device__ __forceinline__ short8 pack8(f32x4 a, f32x4 b){
  union { __hip_bfloat162 h[4]; short8 s; } r;
  r.h[0] = __float22bfloat162_rn(make_float2(a[0], a[1]));
  r.h[1] = __float22bfloat162_rn(make_float2(a[2], a[3]));
  r.h[2] = __float22bfloat162_rn(make_float2(b[0], b[1]));
  r.h[3] = __float22bfloat162_rn(make_float2(b[2], b[3]));
  return r.s;
}

__device__ __forceinline__ void gll16(const void* g, void* l){
  __builtin_amdgcn_global_load_lds(
      (__attribute__((address_space(1))) void*)g,
      (__attribute__((address_space(3))) void*)l, 16, 0, 0);
}

__device__ __forceinline__ void wait_vm8(){  asm volatile("s_waitcnt vmcnt(8)"   ::: "memory"); }
__device__ __forceinline__ void wait_vm0(){  asm volatile("s_waitcnt vmcnt(0)"   ::: "memory"); }
__device__ __forceinline__ void wait_lgkm0(){asm volatile("s_waitcnt lgkmcnt(0)" ::: "memory"); }

#define C2LOG2E 2.8853900817779268f  /* 2*log2(e) */

// ---- K0: merged prepass.
//  blocks [0,1024):    Wk [k][n] f32 -> wkt [n][k] bf16 (transpose+convert)
//  blocks [1024,1152): qup[b][n] = bq[n] + query[b,:] @ Wq[:,n]
//  blocks [1152,5248): key f32 -> keybf bf16, grid-stride x8
__global__ __launch_bounds__(256) void k_pre(const float* __restrict__ Wk, ushort* __restrict__ wkt,
                                             const float* __restrict__ query, const float* __restrict__ Wq,
                                             const float* __restrict__ bq, float* __restrict__ qup,
                                             const float* __restrict__ key, ushort* __restrict__ keybf){
  __shared__ float smem[1056];
  int bid = blockIdx.x;
  int t = threadIdx.x;
  if (bid >= 1152){
    int base = bid - 1152;   // 0..4095
#pragma unroll
    for (int it = 0; it < 8; ++it){
      size_t i = (((size_t)(base + it*4096)) * 256 + t) * 8;
      f32x4 a = *(const f32x4*)(key + i);
      f32x4 b = *(const f32x4*)(key + i + 4);
      *(short8*)(keybf + i) = pack8(a, b);
    }
  } else if (bid < 1024){
    float (*tile)[33] = (float(*)[33])smem;
    int n0 = (bid & 31) * 32, k0 = (bid >> 5) * 32;
    int tx = t & 31, ty = t >> 5;
#pragma unroll
    for (int r = 0; r < 4; ++r)
      tile[ty + 8*r][tx] = Wk[(size_t)(k0 + ty + 8*r) * DM + n0 + tx];
    __syncthreads();
#pragma unroll
    for (int r = 0; r < 4; ++r){
      int n = ty + 8*r;
      wkt[(size_t)(n0 + n) * DM + k0 + tx] = f2bf(tile[tx][n]);
    }
  } else {
    int bb = bid - 1024;
    int b = bb >> 2, nc = bb & 3;
    float* q = smem;
#pragma unroll
    for (int j = 0; j < 4; ++j) q[j*256 + t] = query[(size_t)b*DM + j*256 + t];
    __syncthreads();
    int n = nc*256 + t;
    float acc = bq[n];
#pragma unroll 8
    for (int k = 0; k < DM; ++k) acc += q[k] * Wq[(size_t)k*DM + n];
    qup[(size_t)b*DM + n] = acc;
  }
}

// ---- K2: R8 GEMM + T3/T4 counted-vmcnt double-buffer pipeline (+T5 setprio).
// Per K-step: ds_read frags -> lgkmcnt(0) -> barrier (buffer free) -> STAGE(kt+2)
// into freed half -> setprio(1) 32 MFMA setprio(0) -> vmcnt(8) -> barrier (tile kt+1
// ready; kt+2's 8 loads STAY IN FLIGHT across the barrier). vmcnt(8) semantics
// (oldest-first, m135): outstanding<=16, wait until <=8 => tile kt+1 complete.
// 64KB LDS -> 2 blocks/CU, 8 waves/CU. Swizzle + T1 grouping unchanged from R8.
__global__ __launch_bounds__(256, 2) void k_gemm(
    const ushort* __restrict__ keybf, const ushort* __restrict__ wkt,
    const float* __restrict__ qup, const float* __restrict__ bk,
    const float* __restrict__ wsc, float* __restrict__ scores)
{
  __shared__ ushort ldsA[2][8192];   // 2 x 16 KB
  __shared__ ushort ldsB[2][8192];   // 2 x 16 KB
  const int tid  = threadIdx.x;
  const int lane = tid & 63;
  const int wid  = tid >> 6;
  const int wr   = wid >> 1, wc = wid & 1;
  const int l15  = lane & 15, l16 = lane >> 4;

  // T1: hw round-robins xcd = bid&7; keep 8 ct-siblings of one row-panel on one XCD
  const int bid = blockIdx.x;
  const int xcd = bid & 7;
  const int j   = bid >> 3;             // 0..511
  const int ct  = j & 7;                // column tile / head pair (fast index)
  const int rb  = xcd * 64 + (j >> 3);  // row panel 0..511
  const size_t row0 = (size_t)rb * 128;
  const int b  = rb >> 4;
  const int l0 = (rb & 15) * 128;

  // staging lane geometry: row-in-group g8, pre-swizzled k8 source slot (involution)
  const int g8  = lane >> 3;            // 0..7
  const int sk8 = (lane & 7) ^ g8;
  const ushort* abase = keybf + (row0 + (size_t)(wid*32 + g8)) * DM + sk8*8;
  const ushort* bbase = wkt + (size_t)(ct*128 + wid*32 + g8) * DM + sk8*8;

  // qbc first: its loads are waited-on here, so loop-entry outstanding = glls only
  float qbc[4], wm2[4], wsum = 0.f;
#pragma unroll
  for (int ni = 0; ni < 4; ++ni){
    int n = ct*128 + wc*64 + ni*16 + l15;
    float w = wsc[ni*16 + l15];
    qbc[ni] = (qup[(size_t)b*DM + n] + bk[n]) * C2LOG2E;
    wm2[ni] = -2.f * w;
    wsum   += w;
  }

  f32x4 acc[4][4];
#pragma unroll
  for (int mi = 0; mi < 4; ++mi)
#pragma unroll
    for (int ni = 0; ni < 4; ++ni) acc[mi][ni] = (f32x4){0.f,0.f,0.f,0.f};

  const int sw = (l15 & 7) << 4;   // read-side XOR (row&7)<<4

  // prologue: stage tiles 0 (half0) and 1 (half1); vmcnt(8) -> tile0 (oldest 8) done
#pragma unroll
  for (int c = 0; c < 4; ++c){
    gll16(abase + (size_t)c*8*DM,      (char*)ldsA[0] + wid*4096 + c*1024);
    gll16(bbase + (size_t)c*8*DM,      (char*)ldsB[0] + wid*4096 + c*1024);
  }
#pragma unroll
  for (int c = 0; c < 4; ++c){
    gll16(abase + 64 + (size_t)c*8*DM, (char*)ldsA[1] + wid*4096 + c*1024);
    gll16(bbase + 64 + (size_t)c*8*DM, (char*)ldsB[1] + wid*4096 + c*1024);
  }
  wait_vm8();
  __builtin_amdgcn_s_barrier();

#define KSTEP(KT, DO_STAGE, DO_TAIL, WAITER) do {                                    \
    const char* Ac = (const char*)ldsA[(KT) & 1];                                    \
    const char* Bc = (const char*)ldsB[(KT) & 1];                                    \
    short8 af[4][2], bfr[4][2];                                                      \
    _Pragma("unroll")                                                                \
    for (int mi = 0; mi < 4; ++mi){                                                  \
      int row = wr*64 + mi*16 + l15;                                                 \
      af[mi][0] = *(const short8*)(Ac + row*128 + ((l16*16) ^ sw));                  \
      af[mi][1] = *(const short8*)(Ac + row*128 + ((64 + l16*16) ^ sw));             \
    }                                                                                \
    _Pragma("unroll")                                                                \
    for (int ni = 0; ni < 4; ++ni){                                                  \
      int col = wc*64 + ni*16 + l15;                                                 \
      bfr[ni][0] = *(const short8*)(Bc + col*128 + ((l16*16) ^ sw));                 \
      bfr[ni][1] = *(const short8*)(Bc + col*128 + ((64 + l16*16) ^ sw));            \
    }                                                                                \
    wait_lgkm0();                                                                    \
    __builtin_amdgcn_s_barrier();   /* all waves done reading this half */          \
    if (DO_STAGE){                                                                   \
      char* An = (char*)ldsA[(KT) & 1] + wid*4096;                                   \
      char* Bn = (char*)ldsB[(KT) & 1] + wid*4096;                                   \
      _Pragma("unroll")                                                              \
      for (int c = 0; c < 4; ++c){                                                   \
        gll16(abase + (size_t)((KT)+2)*64 + (size_t)c*8*DM, An + c*1024);            \
        gll16(bbase + (size_t)((KT)+2)*64 + (size_t)c*8*DM, Bn + c*1024);            \
      }                                                                              \
    }                                                                                \
    __builtin_amdgcn_s_setprio(1);                                                   \
    _Pragma("unroll")                                                                \
    for (int kk = 0; kk < 2; ++kk)                                                   \
      _Pragma("unroll")                                                              \
      for (int mi = 0; mi < 4; ++mi)                                                 \
        _Pragma("unroll")                                                            \
        for (int ni = 0; ni < 4; ++ni)                                               \
          acc[mi][ni] = __builtin_amdgcn_mfma_f32_16x16x32_bf16(                     \
              af[mi][kk], bfr[ni][kk], acc[mi][ni], 0, 0, 0);                        \
    __builtin_amdgcn_s_setprio(0);                                                   \
    if (DO_TAIL){ WAITER(); __builtin_amdgcn_s_barrier(); }                          \
  } while(0)

  for (int kt = 0; kt < 14; ++kt)
    KSTEP(kt, 1, 1, wait_vm8);     // kt+2's 8 loads stay in flight across the barrier
  KSTEP(14, 0, 1, wait_vm0);       // drain tile 15
  KSTEP(15, 0, 0, wait_vm0);       // last compute; no tail
#undef KSTEP

  // epilogue: scores = sum_col w*tanh(acc + q + bk), native exp2/rcp form
#pragma unroll
  for (int mi = 0; mi < 4; ++mi){
    f32x4 s = {wsum, wsum, wsum, wsum};
#pragma unroll
    for (int ni = 0; ni < 4; ++ni)
#pragma unroll
      for (int r = 0; r < 4; ++r){
        float a  = fmaf(acc[mi][ni][r], C2LOG2E, qbc[ni]);
        float e  = __builtin_amdgcn_exp2f(a);
        float rc = __builtin_amdgcn_rcpf(e + 1.f);
        s[r] = fmaf(wm2[ni], rc, s[r]);
      }
#pragma unroll
    for (int r = 0; r < 4; ++r){
      float v = s[r];
      v += __shfl_xor(v, 1);
      v += __shfl_xor(v, 2);
      v += __shfl_xor(v, 4);
      v += __shfl_xor(v, 8);
      s[r] = v;
    }
    if (l15 == 0)
      *(f32x4*)(scores + (size_t)(b*NH + ct*2 + wc)*LK + l0 + wr*64 + mi*16 + l16*4) = s;
  }
}

// ---- K3: masked softmax over l -> attn (output #2)
__global__ __launch_bounds__(256) void k_softmax(const float* __restrict__ scores, const int* __restrict__ mask,
                                                 float* __restrict__ attn){
  int bh = blockIdx.x; int b = bh >> 4;
  const float* s = scores + (size_t)bh * LK;
  const int*   m = mask + (size_t)b * LK;
  float*       a = attn + (size_t)bh * LK;
  int t = threadIdx.x;
  __shared__ float red[8];

  float sv[8]; int mv[8];
  float lmax = -1e30f;
#pragma unroll
  for (int j = 0; j < 8; ++j){
    int i = j*256 + t;
    sv[j] = s[i]; mv[j] = m[i];
    if (!mv[j]) lmax = fmaxf(lmax, sv[j]);
  }
#pragma unroll
  for (int off = 32; off >= 1; off >>= 1) lmax = fmaxf(lmax, __shfl_xor(lmax, off));
  if ((t & 63) == 0) red[t >> 6] = lmax;
  __syncthreads();
  lmax = fmaxf(fmaxf(red[0], red[1]), fmaxf(red[2], red[3]));

  float ev[8]; float lsum = 0.f;
#pragma unroll
  for (int j = 0; j < 8; ++j){
    ev[j] = mv[j] ? 0.f : __expf(sv[j] - lmax);
    lsum += ev[j];
  }
#pragma unroll
  for (int off = 32; off >= 1; off >>= 1) lsum += __shfl_xor(lsum, off);
  if ((t & 63) == 0) red[4 + (t >> 6)] = lsum;
  __syncthreads();
  lsum = red[4] + red[5] + red[6] + red[7];
  float inv = 1.f / lsum;
#pragma unroll
  for (int j = 0; j < 8; ++j) a[j*256 + t] = ev[j] * inv;
}

// ---- K4: context partials: part[b,ch,c] = sum_{l in chunk} attn[b,h(c),l] * value[b,l,c]
__global__ __launch_bounds__(256) void k_ctx(const float* __restrict__ value, const float* __restrict__ attn,
                                             float* __restrict__ part){
  int b = blockIdx.x >> 4, ch = blockIdx.x & 15;
  int t = threadIdx.x;
  int c4 = t * 4;
  int head = t >> 4;
  const float* ap = attn + (size_t)(b*NH + head)*LK + ch*128;
  const float* vp = value + ((size_t)b*LK + ch*128)*DM + c4;
  f32x4 acc = {0.f, 0.f, 0.f, 0.f};
#pragma unroll 4
  for (int l = 0; l < 128; ++l){
    float av = ap[l];
    f32x4 v = *(const f32x4*)(vp + (size_t)l*DM);
#pragma unroll
    for (int j = 0; j < 4; ++j) acc[j] += av * v[j];
  }
  *(f32x4*)(part + (size_t)(b*16 + ch)*DM + c4) = acc;
}

// ---- K6: reduce partials -> context; output = context @ Wf + bf (output #1)
__global__ __launch_bounds__(256) void k_out(const float* __restrict__ part, const float* __restrict__ Wf,
                                             const float* __restrict__ bfv, float* __restrict__ out){
  __shared__ float ctx[DM];
  int b = blockIdx.x >> 2, nc = blockIdx.x & 3;
  int t = threadIdx.x;
#pragma unroll
  for (int j = 0; j < 4; ++j){
    int k = j*256 + t;
    float s = 0.f;
#pragma unroll
    for (int c = 0; c < 16; ++c) s += part[(size_t)(b*16 + c)*DM + k];
    ctx[k] = s;
  }
  __syncthreads();
  int n = nc*256 + t;
  float acc = bfv[n];
#pragma unroll 8
  for (int k = 0; k < DM; ++k) acc += ctx[k] * Wf[(size_t)k*DM + n];
  out[(size_t)b*DM + n] = acc;
}

extern "C" void kernel_launch(void* const* d_in, const int* in_sizes, int n_in,
                              void* d_out, int out_size, void* d_ws, size_t ws_size,
                              hipStream_t stream){
  (void)in_sizes; (void)n_in; (void)out_size; (void)ws_size;
  const float* key   = (const float*)d_in[0];
  const float* value = (const float*)d_in[1];
  const float* query = (const float*)d_in[2];
  const int*   mask  = (const int*)d_in[3];
  const float* Wk    = (const float*)d_in[4];
  const float* bk    = (const float*)d_in[5];
  const float* Wq    = (const float*)d_in[6];
  const float* bq    = (const float*)d_in[7];
  const float* wsc   = (const float*)d_in[8];
  // d_in[9] = b_score: softmax-invariant, unused
  const float* Wf    = (const float*)d_in[10];
  const float* bfv   = (const float*)d_in[11];

  float* out0 = (float*)d_out;
  float* attn = out0 + (size_t)B_ * DM;   // [B,H,1,Lk] region

  char* ws = (char*)d_ws;
  ushort* wkt  = (ushort*)(ws);                                    // 2 MB
  float*  qup  = (float*)(ws + (2u<<20));                          // 128 KB
  float*  scr  = (float*)(ws + (2u<<20) + (128u<<10));             // 4 MB
  float*  part = (float*)(ws + (2u<<20) + (128u<<10) + (4u<<20));  // 2 MB
  const size_t base = (2u<<20) + (128u<<10) + (4u<<20) + (2u<<20); // 8.125 MB
  ushort* keybf = (ushort*)(ws + base);                            // 128 MB

  k_pre<<<5248, 256, 0, stream>>>(Wk, wkt, query, Wq, bq, qup, key, keybf);
  k_gemm<<<4096, 256, 0, stream>>>(keybf, wkt, qup, bk, wsc, scr);
  k_softmax<<<512, 256, 0, stream>>>(scr, mask, attn);
  k_ctx<<<512, 256, 0, stream>>>(value, attn, part);
  k_out<<<128, 256, 0, stream>>>(part, Wf, bfv, out0);
}